// Round 11
// baseline (391.291 us; speedup 1.0000x reference)
//
#include <hip/hip_runtime.h>
#include <hip/hip_fp16.h>

#define NN 100000
#define NE 3200000
#define NG 1024
#define NP 100352            // NN padded to multiple of 256
#define NBUCK 391            // ceil(NN/256) buckets of 256 dst nodes
#define NBLK 256
#define CHUNK ((NE + NBLK - 1) / NBLK)
#define WINCAP 12288
#define NSL 25               // src slices (src>>12), 25*4096 >= NN
#define SLROWS 4096
#define NPB 392              // dst nodes per agg_lds block (NP/256)

// ---------- fp16 pack/unpack helpers ----------
static __device__ inline void addu2(float* a, uint2 u) {
    __half2* ph = reinterpret_cast<__half2*>(&u);
    float2 f0 = __half22float2(ph[0]);
    float2 f1 = __half22float2(ph[1]);
    a[0] += f0.x; a[1] += f0.y; a[2] += f1.x; a[3] += f1.y;
}
static __device__ inline uint2 pack4(float a, float b, float c, float d) {
    __half2 lo = __floats2half2_rn(a, b);
    __half2 hi = __floats2half2_rn(c, d);
    uint2 u;
    u.x = *reinterpret_cast<unsigned int*>(&lo);
    u.y = *reinterpret_cast<unsigned int*>(&hi);
    return u;
}

// ---- k1: per-bucket edge histogram ----
__global__ void hist_buckets(const int* __restrict__ dst, int* __restrict__ bcnt) {
    __shared__ int sm[NBUCK];
    int tid = threadIdx.x;
    for (int i = tid; i < NBUCK; i += 256) sm[i] = 0;
    __syncthreads();
    int s = blockIdx.x * CHUNK, e = min(NE, s + CHUNK);
    for (int i = s + tid; i < e; i += 256) atomicAdd(&sm[dst[i] >> 8], 1);
    __syncthreads();
    for (int i = tid; i < NBUCK; i += 256)
        if (sm[i]) atomicAdd(&bcnt[i], sm[i]);
}

// ---- k2: exclusive scan of bucket counts ----
__global__ void scan_buckets(const int* __restrict__ bcnt, int* __restrict__ bbase) {
    __shared__ int tmp[512];
    int tid = threadIdx.x;
    int v = (tid < NBUCK) ? bcnt[tid] : 0;
    tmp[tid] = v;
    __syncthreads();
    for (int off = 1; off < 512; off <<= 1) {
        int t = (tid >= off) ? tmp[tid - off] : 0;
        __syncthreads();
        tmp[tid] += t;
        __syncthreads();
    }
    if (tid < NBUCK) bbase[tid] = tmp[tid] - v;
}

// ---- k3: partition edges into bucket regions, packed (dst&255)<<17 | src ----
__global__ void partition(const int* __restrict__ src, const int* __restrict__ dst,
                          const int* __restrict__ bbase, int* __restrict__ bfill,
                          int* __restrict__ part) {
    __shared__ int smh[NBUCK];
    __shared__ int smc[NBUCK];
    int tid = threadIdx.x;
    for (int i = tid; i < NBUCK; i += 256) smh[i] = 0;
    __syncthreads();
    int s = blockIdx.x * CHUNK, e = min(NE, s + CHUNK);
    for (int i = s + tid; i < e; i += 256) atomicAdd(&smh[dst[i] >> 8], 1);
    __syncthreads();
    for (int i = tid; i < NBUCK; i += 256) {
        int c = smh[i];
        smc[i] = c ? (bbase[i] + atomicAdd(&bfill[i], c)) : 0;
    }
    __syncthreads();
    for (int i = s + tid; i < e; i += 256) {
        int d = dst[i];
        int b = d >> 8;
        int p = atomicAdd(&smc[b], 1);
        part[p] = src[i] | ((d & 255) << 17);
    }
}

// ---- k4: per-bucket CSR build, counting sort by (dst_local, src>>12) so each
//      node's edge list is SLICE-SORTED (required by agg_lds cursor walk).
//      Also computes dis and the packed {class, fp16 dis} table pk. ----
__global__ void build_csr(const int* __restrict__ part, const int* __restrict__ bbase,
                          const int* __restrict__ bcnt, const int* __restrict__ types,
                          const int* __restrict__ pos, int* __restrict__ cnt,
                          int* __restrict__ offs, float* __restrict__ dis,
                          unsigned int* __restrict__ pk, int* __restrict__ srcs) {
    __shared__ int cnt2[256 * NSL];   // 25.6 KB
    __shared__ int cur2[256 * NSL];   // 25.6 KB
    __shared__ int tmp[256];
    __shared__ int win[WINCAP];       // 49 KB  (total ~101 KB)
    int b = blockIdx.x, tid = threadIdx.x;
    int base = bbase[b], m = bcnt[b];
    for (int i = tid; i < 256 * NSL; i += 256) cnt2[i] = 0;
    __syncthreads();
    for (int i = tid; i < m; i += 256) {
        int p = part[base + i];
        int key = (p >> 17) * NSL + ((p & 0x1FFFF) >> 12);
        atomicAdd(&cnt2[key], 1);
    }
    __syncthreads();
    // per-thread serial exclusive scan over its node's 25 slice bins
    int run = 0;
    for (int j = 0; j < NSL; j++) {
        int c = cnt2[tid * NSL + j];
        cur2[tid * NSL + j] = run;
        run += c;
    }
    int v = run;
    tmp[tid] = v;
    __syncthreads();
    for (int off = 1; off < 256; off <<= 1) {
        int t = (tid >= off) ? tmp[tid - off] : 0;
        __syncthreads();
        tmp[tid] += t;
        __syncthreads();
    }
    int excl = tmp[tid] - v;
    int n = b * 256 + tid;
    if (n < NN) {
        cnt[n] = v;
        offs[n] = base + excl;
        float dv = rsqrtf((float)v + 1.0f);
        dis[n] = dv;
        int cls = types[n] * 3 + pos[n];
        pk[n] = ((unsigned int)cls << 16) |
                (unsigned int)__half_as_ushort(__float2half_rn(dv));
    }
    for (int j = 0; j < NSL; j++) cur2[tid * NSL + j] += excl;
    __syncthreads();
    if (m <= WINCAP) {
        for (int i = tid; i < m; i += 256) {
            int p = part[base + i];
            int key = (p >> 17) * NSL + ((p & 0x1FFFF) >> 12);
            int l = atomicAdd(&cur2[key], 1);
            win[l] = p & 0x1FFFF;
        }
        __syncthreads();
        for (int i = tid; i < m; i += 256) srcs[base + i] = win[i];
    } else {
        for (int i = tid; i < m; i += 256) {
            int p = part[base + i];
            int key = (p >> 17) * NSL + ((p & 0x1FFFF) >> 12);
            int l = atomicAdd(&cur2[key], 1);
            srcs[base + l] = p & 0x1FFFF;
        }
    }
}

// ---- layer 0 fused: 9-class dis-histogram agg (4B/edge pk gather) ----
// (unchanged from round 10; order-agnostic so slice-sorted srcs is fine)
__global__ void agg0_tf(const unsigned int* __restrict__ pk,
                        const int* __restrict__ srcs, const int* __restrict__ offs,
                        const int* __restrict__ cnt, const float* __restrict__ dis,
                        const float* __restrict__ W1, const float* __restrict__ b1,
                        const float* __restrict__ W2, const float* __restrict__ b2,
                        const float* __restrict__ Wg0, const float* __restrict__ bg0,
                        const float* __restrict__ Wg1, uint2* __restrict__ hs_out) {
    __shared__ float sV[144];     // V[c][f] = (E[c] @ Wg0)[f], c=ty*3+pp
    __shared__ float sW[256];     // Wg1
    int tid = threadIdx.x;
    sW[tid] = Wg1[tid];
    if (tid < 144) {
        int c = tid >> 4, f = tid & 15;
        int ty = c / 3, pp = c % 3;
        float a = 0.f;
#pragma unroll
        for (int k = 0; k < 16; k++) a += (W1[ty * 16 + k] + b1[k]) * Wg0[k * 16 + f];
#pragma unroll
        for (int k = 0; k < 16; k++) a += (W2[pp * 16 + k] + b2[k]) * Wg0[(16 + k) * 16 + f];
        sV[tid] = a;
    }
    __syncthreads();
    int gid = blockIdx.x * 256 + tid;
    int n = gid >> 1, h = gid & 1;
    if (n >= NN) return;
    int beg = offs[n], deg = cnt[n];
    int half = deg >> 1;
    int lo = beg + (h ? half : 0);
    int hi = beg + (h ? deg : half);

    float a0 = 0.f, a1 = 0.f, a2 = 0.f, a3 = 0.f, a4 = 0.f;
    float a5 = 0.f, a6 = 0.f, a7 = 0.f, a8 = 0.f;
#define ACCP(P)                                                       \
    do {                                                              \
        unsigned int _p = (P);                                        \
        int _c = (int)(_p >> 16);                                     \
        float _d = __half2float(__ushort_as_half((unsigned short)(_p & 0xFFFFu))); \
        a0 += (_c == 0) ? _d : 0.f;  a1 += (_c == 1) ? _d : 0.f;      \
        a2 += (_c == 2) ? _d : 0.f;  a3 += (_c == 3) ? _d : 0.f;      \
        a4 += (_c == 4) ? _d : 0.f;  a5 += (_c == 5) ? _d : 0.f;      \
        a6 += (_c == 6) ? _d : 0.f;  a7 += (_c == 7) ? _d : 0.f;      \
        a8 += (_c == 8) ? _d : 0.f;                                   \
    } while (0)
    int i = lo;
    for (; i + 4 <= hi; i += 4) {
        int s0 = srcs[i + 0];
        int s1 = srcs[i + 1];
        int s2 = srcs[i + 2];
        int s3 = srcs[i + 3];
        unsigned int p0 = pk[s0];
        unsigned int p1 = pk[s1];
        unsigned int p2 = pk[s2];
        unsigned int p3 = pk[s3];
        ACCP(p0); ACCP(p1); ACCP(p2); ACCP(p3);
    }
    for (; i < hi; i++) ACCP(pk[srcs[i]]);

    a0 += __shfl_xor(a0, 1); a1 += __shfl_xor(a1, 1); a2 += __shfl_xor(a2, 1);
    a3 += __shfl_xor(a3, 1); a4 += __shfl_xor(a4, 1); a5 += __shfl_xor(a5, 1);
    a6 += __shfl_xor(a6, 1); a7 += __shfl_xor(a7, 1); a8 += __shfl_xor(a8, 1);
    ACCP(pk[n]);              // self loop (both lanes, identical)
#undef ACCP

    float dn = dis[n];
    float acc[9] = {a0, a1, a2, a3, a4, a5, a6, a7, a8};
    float pre[16];
#pragma unroll
    for (int f = 0; f < 16; f++) {
        float a = 0.f;
#pragma unroll
        for (int c = 0; c < 9; c++) a += acc[c] * sV[c * 16 + f];
        a = fmaf(a, dn, bg0[f]);
        pre[f] = fmaxf(a, 0.f);   // relu
    }
    if (h == 0) {
        float hv[16];
#pragma unroll
        for (int f2 = 0; f2 < 16; f2++) hv[f2] = 0.f;
#pragma unroll
        for (int f = 0; f < 16; f++) {
            float z = pre[f];
#pragma unroll
            for (int f2 = 0; f2 < 16; f2++) hv[f2] += z * sW[f * 16 + f2];
        }
        uint2* op = hs_out + (size_t)n * 4;
#pragma unroll
        for (int q = 0; q < 4; q++)
            op[q] = pack4(hv[q * 4] * dn, hv[q * 4 + 1] * dn,
                          hv[q * 4 + 2] * dn, hv[q * 4 + 3] * dn);
    }
}

// ---- slice-LDS aggregation + (transform | pool) ----
// 256 blocks (1/CU) x 512 threads; block owns NPB=392 dst nodes (1/thread).
// Per slice: STREAM 128KB of hs into LDS (sequential global loads -> no
// random transactions), then cursor-walk slice-sorted edge lists with
// ds_read_b64 (random LDS reads ~6cy, <=4-way conflicts). Rounds 0-10
// established the wall: 1 random GLOBAL transaction/edge @ ~17cy/CU.
// Row stored as 4x8B regions: writes (consecutive rows) and reads (random
// rows) both land <=4-way.
template <int RELU, int FUSE_POOL>
__global__ __launch_bounds__(512) void agg_lds(
        const uint2* __restrict__ hs, const int* __restrict__ srcs,
        const int* __restrict__ offs, const int* __restrict__ cnt,
        const float* __restrict__ dis, const float* __restrict__ bias,
        const float* __restrict__ Wn, uint2* __restrict__ hs_out,
        const int* __restrict__ batch, float* __restrict__ pool,
        int* __restrict__ gcnt) {
    __shared__ uint2 sl[4 * SLROWS];   // 128 KiB
    int tid = threadIdx.x, b = blockIdx.x;
    int n = b * NPB + tid;
    bool act = (tid < NPB) && (n < NN);
    int beg = 0, deg = 0;
    float dn = 0.f;
    if (act) { beg = offs[n]; deg = cnt[n]; dn = dis[n]; }
    float acc[16];
#pragma unroll
    for (int j = 0; j < 16; j++) acc[j] = 0.f;
    int cur = 0;
    int sv = (act && deg > 0) ? srcs[beg] : 0x7FFFFFFF;
    const uint4* hs4 = (const uint4*)hs;

    for (int s = 0; s < NSL; s++) {
        __syncthreads();
#pragma unroll
        for (int k = 0; k < 8; k++) {
            int r = tid + k * 512;
            uint4 A = hs4[(size_t)(s * SLROWS + r) * 2];
            uint4 B = hs4[(size_t)(s * SLROWS + r) * 2 + 1];
            sl[r]              = make_uint2(A.x, A.y);
            sl[SLROWS + r]     = make_uint2(A.z, A.w);
            sl[2 * SLROWS + r] = make_uint2(B.x, B.y);
            sl[3 * SLROWS + r] = make_uint2(B.z, B.w);
        }
        __syncthreads();
        int hi = (s + 1) * SLROWS;
        while (sv < hi) {
            int rl = sv - s * SLROWS;
            uint2 p0 = sl[rl];
            uint2 p1 = sl[SLROWS + rl];
            uint2 p2 = sl[2 * SLROWS + rl];
            uint2 p3 = sl[3 * SLROWS + rl];
            addu2(acc + 0, p0);  addu2(acc + 4, p1);
            addu2(acc + 8, p2);  addu2(acc + 12, p3);
            cur++;
            sv = (cur < deg) ? srcs[beg + cur] : 0x7FFFFFFF;
        }
    }

    // self loop + bias (+relu)
    float z[16];
    if (act) {
        const uint4* hp = (const uint4*)(hs + (size_t)n * 4);
        uint4 ha = hp[0], hb = hp[1];
        addu2(acc + 0, make_uint2(ha.x, ha.y));
        addu2(acc + 4, make_uint2(ha.z, ha.w));
        addu2(acc + 8, make_uint2(hb.x, hb.y));
        addu2(acc + 12, make_uint2(hb.z, hb.w));
#pragma unroll
        for (int j = 0; j < 16; j++) {
            float a = fmaf(acc[j], dn, bias[j]);
            z[j] = RELU ? fmaxf(a, 0.f) : a;
        }
    }
    if (FUSE_POOL) {
        if (act) {
            float ssum = 0.f;
#pragma unroll
            for (int j = 0; j < 16; j++) ssum += z[j] * Wn[j];
            int g = batch[n];
            atomicAdd(&pool[g], ssum);
            atomicAdd(&gcnt[g], 1);
        }
    } else {
        __syncthreads();
        float* sW = (float*)sl;          // reuse slice LDS for Wn
        if (tid < 256) sW[tid] = Wn[tid];
        __syncthreads();
        if (act) {
            float hv[16];
#pragma unroll
            for (int f2 = 0; f2 < 16; f2++) hv[f2] = 0.f;
#pragma unroll
            for (int f = 0; f < 16; f++) {
                float zf = z[f];
#pragma unroll
                for (int f2 = 0; f2 < 16; f2++) hv[f2] += zf * sW[f * 16 + f2];
            }
            uint2 t0 = pack4(hv[0] * dn, hv[1] * dn, hv[2] * dn, hv[3] * dn);
            uint2 t1 = pack4(hv[4] * dn, hv[5] * dn, hv[6] * dn, hv[7] * dn);
            uint2 t2 = pack4(hv[8] * dn, hv[9] * dn, hv[10] * dn, hv[11] * dn);
            uint2 t3 = pack4(hv[12] * dn, hv[13] * dn, hv[14] * dn, hv[15] * dn);
            uint4* op = (uint4*)(hs_out + (size_t)n * 4);
            op[0] = make_uint4(t0.x, t0.y, t1.x, t1.y);
            op[1] = make_uint4(t2.x, t2.y, t3.x, t3.y);
        }
    }
}

__global__ void finalize(const float* __restrict__ pool, const int* __restrict__ gcnt,
                         const float* __restrict__ bo, float* __restrict__ out) {
    int g = blockIdx.x * 256 + threadIdx.x;
    if (g < NG) {
        float c = fmaxf((float)gcnt[g], 1.0f);
        out[g] = pool[g] / c + bo[0];
    }
}

extern "C" void kernel_launch(void* const* d_in, const int* in_sizes, int n_in,
                              void* d_out, int out_size, void* d_ws, size_t ws_size,
                              hipStream_t stream) {
    const int*   types = (const int*)d_in[0];
    const int*   pos   = (const int*)d_in[1];
    const int*   ei    = (const int*)d_in[2];   // [2, E]: src then dst
    const int*   batch = (const int*)d_in[3];
    const float* W1  = (const float*)d_in[4];
    const float* b1  = (const float*)d_in[5];
    const float* W2  = (const float*)d_in[6];
    const float* b2  = (const float*)d_in[7];
    const float* Wg0 = (const float*)d_in[8];
    const float* bg0 = (const float*)d_in[9];
    const float* Wg1 = (const float*)d_in[10];
    const float* bg1 = (const float*)d_in[11];
    const float* Wg2 = (const float*)d_in[12];
    const float* bg2 = (const float*)d_in[13];
    const float* Wo  = (const float*)d_in[14];
    const float* bo  = (const float*)d_in[15];
    float* out = (float*)d_out;

    const int* esrc = ei;
    const int* edst = ei + NE;

    // ---- workspace layout (ints) ----
    int*   bcnt  = (int*)d_ws;                   // 512  (zeroed)
    int*   bfill = bcnt + 512;                   // 512  (zeroed)
    float* pool  = (float*)(bfill + 512);        // 1024 (zeroed)
    int*   gcnt  = (int*)(pool + NG);            // 1024 (zeroed)
    int*   bbase = gcnt + NG;                    // 512
    int*   cnt   = bbase + 512;                  // NP
    int*   offs  = cnt + NP;                     // NP
    float* dis   = (float*)(offs + NP);          // NP
    unsigned int* pk = (unsigned int*)(dis + NP);// NP  ({class,fp16 dis} table)
    int*   srcs  = (int*)(pk + NP);              // NE
    int*   part  = srcs + NE;                    // NE  (hs buffers alias this)
    uint2* hsA   = (uint2*)part;                 // rows 0..204800 available (6.4 MB)
    uint2* hsB   = (uint2*)(part + NE / 2);      // rows 0..204800 available (6.4 MB)
    (void)ws_size; (void)n_in; (void)in_sizes; (void)out_size;

    hipMemsetAsync(d_ws, 0, (size_t)(1024 + 2 * NG) * sizeof(int), stream);

    const int QB2 = (NN * 2 + 255) / 256;        // 782

    hist_buckets<<<NBLK, 256, 0, stream>>>(edst, bcnt);
    scan_buckets<<<1, 512, 0, stream>>>(bcnt, bbase);
    partition<<<NBLK, 256, 0, stream>>>(esrc, edst, bbase, bfill, part);
    build_csr<<<NBUCK, 256, 0, stream>>>(part, bbase, bcnt, types, pos,
                                         cnt, offs, dis, pk, srcs);

    // layer 0 (fused rank-9): 4B/edge pk gather -> hs1 = (relu(...)@Wg1)*dis
    agg0_tf<<<QB2, 256, 0, stream>>>(pk, srcs, offs, cnt, dis, W1, b1, W2, b2,
                                     Wg0, bg0, Wg1, hsA);
    // layer 1: slice-LDS agg + relu + transform Wg2 -> hsB
    agg_lds<1, 0><<<256, 512, 0, stream>>>(hsA, srcs, offs, cnt, dis, bg1, Wg2,
                                           hsB, batch, pool, gcnt);
    // layer 2: slice-LDS agg (no relu) + Wo dot + pool
    agg_lds<0, 1><<<256, 512, 0, stream>>>(hsB, srcs, offs, cnt, dis, bg2, Wo,
                                           hsA /*unused*/, batch, pool, gcnt);

    finalize<<<(NG + 255) / 256, 256, 0, stream>>>(pool, gcnt, bo, out);
}

// Round 12
// 325.688 us; speedup vs baseline: 1.2014x; 1.2014x over previous
//
#include <hip/hip_runtime.h>
#include <hip/hip_fp16.h>

#define NN 100000
#define NE 3200000
#define NG 1024
#define NP 100352            // NN padded to multiple of 256
#define NBUCK 391            // ceil(NN/256) buckets of 256 dst nodes
#define NBLK 256
#define CHUNK ((NE + NBLK - 1) / NBLK)
#define WINCAP 12288

// ---------- fp16 pack/unpack helpers ----------
static __device__ inline void acc_u2(float4& acc, uint2 u) {
    __half2* ph = reinterpret_cast<__half2*>(&u);
    float2 lo = __half22float2(ph[0]);
    float2 hi = __half22float2(ph[1]);
    acc.x += lo.x; acc.y += lo.y; acc.z += hi.x; acc.w += hi.y;
}
static __device__ inline uint2 pack4(float a, float b, float c, float d) {
    __half2 lo = __floats2half2_rn(a, b);
    __half2 hi = __floats2half2_rn(c, d);
    uint2 u;
    u.x = *reinterpret_cast<unsigned int*>(&lo);
    u.y = *reinterpret_cast<unsigned int*>(&hi);
    return u;
}
static __device__ inline float4 shfl_xor4(float4 v, int m) {
    float4 r;
    r.x = __shfl_xor(v.x, m); r.y = __shfl_xor(v.y, m);
    r.z = __shfl_xor(v.z, m); r.w = __shfl_xor(v.w, m);
    return r;
}

// ---- k1: per-bucket edge histogram ----
__global__ void hist_buckets(const int* __restrict__ dst, int* __restrict__ bcnt) {
    __shared__ int sm[NBUCK];
    int tid = threadIdx.x;
    for (int i = tid; i < NBUCK; i += 256) sm[i] = 0;
    __syncthreads();
    int s = blockIdx.x * CHUNK, e = min(NE, s + CHUNK);
    for (int i = s + tid; i < e; i += 256) atomicAdd(&sm[dst[i] >> 8], 1);
    __syncthreads();
    for (int i = tid; i < NBUCK; i += 256)
        if (sm[i]) atomicAdd(&bcnt[i], sm[i]);
}

// ---- k2: exclusive scan of bucket counts ----
__global__ void scan_buckets(const int* __restrict__ bcnt, int* __restrict__ bbase) {
    __shared__ int tmp[512];
    int tid = threadIdx.x;
    int v = (tid < NBUCK) ? bcnt[tid] : 0;
    tmp[tid] = v;
    __syncthreads();
    for (int off = 1; off < 512; off <<= 1) {
        int t = (tid >= off) ? tmp[tid - off] : 0;
        __syncthreads();
        tmp[tid] += t;
        __syncthreads();
    }
    if (tid < NBUCK) bbase[tid] = tmp[tid] - v;
}

// ---- k3: partition edges into bucket regions, packed (dst&255)<<17 | src ----
__global__ void partition(const int* __restrict__ src, const int* __restrict__ dst,
                          const int* __restrict__ bbase, int* __restrict__ bfill,
                          int* __restrict__ part) {
    __shared__ int smh[NBUCK];
    __shared__ int smc[NBUCK];
    int tid = threadIdx.x;
    for (int i = tid; i < NBUCK; i += 256) smh[i] = 0;
    __syncthreads();
    int s = blockIdx.x * CHUNK, e = min(NE, s + CHUNK);
    for (int i = s + tid; i < e; i += 256) atomicAdd(&smh[dst[i] >> 8], 1);
    __syncthreads();
    for (int i = tid; i < NBUCK; i += 256) {
        int c = smh[i];
        smc[i] = c ? (bbase[i] + atomicAdd(&bfill[i], c)) : 0;
    }
    __syncthreads();
    for (int i = s + tid; i < e; i += 256) {
        int d = dst[i];
        int b = d >> 8;
        int p = atomicAdd(&smc[b], 1);
        part[p] = src[i] | ((d & 255) << 17);
    }
}

// ---- k4: per-bucket CSR build in LDS; also computes dis and the packed
//      per-node {class, fp16(dis)} table pk used by the layer-0 histogram agg ----
__global__ void build_csr(const int* __restrict__ part, const int* __restrict__ bbase,
                          const int* __restrict__ bcnt, const int* __restrict__ types,
                          const int* __restrict__ pos, int* __restrict__ cnt,
                          int* __restrict__ offs, float* __restrict__ dis,
                          unsigned int* __restrict__ pk, int* __restrict__ srcs) {
    __shared__ int sm_cnt[256];
    __shared__ int sm_off[256];
    __shared__ int sm_cur[256];
    __shared__ int sm_win[WINCAP];
    int b = blockIdx.x, tid = threadIdx.x;
    int base = bbase[b], m = bcnt[b];
    sm_cnt[tid] = 0;
    __syncthreads();
    for (int i = tid; i < m; i += 256) atomicAdd(&sm_cnt[part[base + i] >> 17], 1);
    __syncthreads();
    int v = sm_cnt[tid];
    sm_off[tid] = v;
    __syncthreads();
    for (int off = 1; off < 256; off <<= 1) {
        int t = (tid >= off) ? sm_off[tid - off] : 0;
        __syncthreads();
        sm_off[tid] += t;
        __syncthreads();
    }
    int excl = sm_off[tid] - v;
    int n = b * 256 + tid;
    if (n < NN) {
        cnt[n] = v;
        offs[n] = base + excl;
        float dv = rsqrtf((float)v + 1.0f);
        dis[n] = dv;
        int cls = types[n] * 3 + pos[n];
        __half hd = __float2half_rn(dv);
        pk[n] = ((unsigned int)cls << 16) | (unsigned int)__half_as_ushort(hd);
    }
    sm_cur[tid] = excl;
    __syncthreads();
    if (m <= WINCAP) {
        for (int i = tid; i < m; i += 256) {
            int p = part[base + i];
            int l = atomicAdd(&sm_cur[p >> 17], 1);
            sm_win[l] = p & 0x1FFFF;
        }
        __syncthreads();
        for (int i = tid; i < m; i += 256) srcs[base + i] = sm_win[i];
    } else {
        for (int i = tid; i < m; i += 256) {
            int p = part[base + i];
            int l = atomicAdd(&sm_cur[p >> 17], 1);
            srcs[base + l] = p & 0x1FFFF;
        }
    }
}

// ---- layer 0 fused: 9-class dis-histogram agg + (agg9@V) + bias + relu + @Wg1 ----
// Rank-9 structure: z0[n] depends only on (types,pos) in 3x3, so
// hs0[src] = dis[src] * V[class(src)] with V = E @ Wg0 (9x16, built in LDS).
// Per edge we gather only 4B (pk = {class,fp16 dis}) from a 400KB L2-resident
// table. 2 threads per node: h = gid&1 walks half the edge list; fold via shfl.
__global__ void agg0_tf(const unsigned int* __restrict__ pk,
                        const int* __restrict__ srcs, const int* __restrict__ offs,
                        const int* __restrict__ cnt, const float* __restrict__ dis,
                        const float* __restrict__ W1, const float* __restrict__ b1,
                        const float* __restrict__ W2, const float* __restrict__ b2,
                        const float* __restrict__ Wg0, const float* __restrict__ bg0,
                        const float* __restrict__ Wg1, uint2* __restrict__ hs_out) {
    __shared__ float sV[144];     // V[c][f] = (E[c] @ Wg0)[f], c=ty*3+pp
    __shared__ float sW[256];     // Wg1
    int tid = threadIdx.x;
    sW[tid] = Wg1[tid];
    if (tid < 144) {
        int c = tid >> 4, f = tid & 15;
        int ty = c / 3, pp = c % 3;
        float a = 0.f;
#pragma unroll
        for (int k = 0; k < 16; k++) a += (W1[ty * 16 + k] + b1[k]) * Wg0[k * 16 + f];
#pragma unroll
        for (int k = 0; k < 16; k++) a += (W2[pp * 16 + k] + b2[k]) * Wg0[(16 + k) * 16 + f];
        sV[tid] = a;
    }
    __syncthreads();
    int gid = blockIdx.x * 256 + tid;
    int n = gid >> 1, h = gid & 1;
    if (n >= NN) return;
    int beg = offs[n], deg = cnt[n];
    int half = deg >> 1;
    int lo = beg + (h ? half : 0);
    int hi = beg + (h ? deg : half);

    float a0 = 0.f, a1 = 0.f, a2 = 0.f, a3 = 0.f, a4 = 0.f;
    float a5 = 0.f, a6 = 0.f, a7 = 0.f, a8 = 0.f;
#define ACCP(P)                                                       \
    do {                                                              \
        unsigned int _p = (P);                                        \
        int _c = (int)(_p >> 16);                                     \
        float _d = __half2float(__ushort_as_half((unsigned short)(_p & 0xFFFFu))); \
        a0 += (_c == 0) ? _d : 0.f;  a1 += (_c == 1) ? _d : 0.f;      \
        a2 += (_c == 2) ? _d : 0.f;  a3 += (_c == 3) ? _d : 0.f;      \
        a4 += (_c == 4) ? _d : 0.f;  a5 += (_c == 5) ? _d : 0.f;      \
        a6 += (_c == 6) ? _d : 0.f;  a7 += (_c == 7) ? _d : 0.f;      \
        a8 += (_c == 8) ? _d : 0.f;                                   \
    } while (0)
    int i = lo;
    for (; i + 4 <= hi; i += 4) {
        int s0 = srcs[i + 0];
        int s1 = srcs[i + 1];
        int s2 = srcs[i + 2];
        int s3 = srcs[i + 3];
        unsigned int p0 = pk[s0];
        unsigned int p1 = pk[s1];
        unsigned int p2 = pk[s2];
        unsigned int p3 = pk[s3];
        ACCP(p0); ACCP(p1); ACCP(p2); ACCP(p3);
    }
    for (; i < hi; i++) ACCP(pk[srcs[i]]);

    // fold the two edge-halves (lanes gid and gid^1 share the node)
    a0 += __shfl_xor(a0, 1); a1 += __shfl_xor(a1, 1); a2 += __shfl_xor(a2, 1);
    a3 += __shfl_xor(a3, 1); a4 += __shfl_xor(a4, 1); a5 += __shfl_xor(a5, 1);
    a6 += __shfl_xor(a6, 1); a7 += __shfl_xor(a7, 1); a8 += __shfl_xor(a8, 1);
    ACCP(pk[n]);              // self loop (both lanes, identical)
#undef ACCP

    float dn = dis[n];
    float acc[9] = {a0, a1, a2, a3, a4, a5, a6, a7, a8};
    float pre[16];
#pragma unroll
    for (int f = 0; f < 16; f++) {
        float a = 0.f;
#pragma unroll
        for (int c = 0; c < 9; c++) a += acc[c] * sV[c * 16 + f];
        a = fmaf(a, dn, bg0[f]);
        pre[f] = fmaxf(a, 0.f);   // relu
    }
    if (h == 0) {
        float hv[16];
#pragma unroll
        for (int f2 = 0; f2 < 16; f2++) hv[f2] = 0.f;
#pragma unroll
        for (int f = 0; f < 16; f++) {
            float z = pre[f];
#pragma unroll
            for (int f2 = 0; f2 < 16; f2++) hv[f2] += z * sW[f * 16 + f2];
        }
        uint2* op = hs_out + (size_t)n * 4;
#pragma unroll
        for (int q = 0; q < 4; q++)
            op[q] = pack4(hv[q * 4] * dn, hv[q * 4 + 1] * dn,
                          hv[q * 4 + 2] * dn, hv[q * 4 + 3] * dn);
    }
}

// ---- fused aggregate + (transform | pool): 4 threads per node (round-0 verbatim) ----
template <int RELU, int FUSE_POOL>
__global__ void agg_tf(const uint2* __restrict__ hs, const int* __restrict__ srcs,
                       const int* __restrict__ offs, const int* __restrict__ cnt,
                       const float* __restrict__ dis, const float* __restrict__ bias,
                       const float* __restrict__ Wn, uint2* __restrict__ hs_out,
                       const int* __restrict__ batch,
                       float* __restrict__ pool, int* __restrict__ gcnt) {
    __shared__ float sW[256];
    int tid = threadIdx.x;
    if (!FUSE_POOL) {
        sW[tid] = Wn[tid];
        __syncthreads();
    }
    int gid = blockIdx.x * 256 + tid;
    int n = gid >> 2, q = gid & 3;
    if (n >= NN) return;
    int beg = offs[n], deg = cnt[n];
    float dn = dis[n];
    float4 acc = make_float4(0.f, 0.f, 0.f, 0.f);
    int i = 0;
    for (; i + 4 <= deg; i += 4) {
        int s0 = srcs[beg + i + 0];
        int s1 = srcs[beg + i + 1];
        int s2 = srcs[beg + i + 2];
        int s3 = srcs[beg + i + 3];
        uint2 a0 = hs[(size_t)s0 * 4 + q];
        uint2 a1 = hs[(size_t)s1 * 4 + q];
        uint2 a2 = hs[(size_t)s2 * 4 + q];
        uint2 a3 = hs[(size_t)s3 * 4 + q];
        acc_u2(acc, a0); acc_u2(acc, a1); acc_u2(acc, a2); acc_u2(acc, a3);
    }
    for (; i < deg; i++) {
        int s = srcs[beg + i];
        acc_u2(acc, hs[(size_t)s * 4 + q]);
    }
    acc_u2(acc, hs[(size_t)n * 4 + q]);   // self loop (hs = h*dis, self coef dn*dn)
    float4 b4 = ((const float4*)bias)[q];
    acc.x = fmaf(acc.x, dn, b4.x);
    acc.y = fmaf(acc.y, dn, b4.y);
    acc.z = fmaf(acc.z, dn, b4.z);
    acc.w = fmaf(acc.w, dn, b4.w);
    if (RELU) {
        acc.x = fmaxf(acc.x, 0.f); acc.y = fmaxf(acc.y, 0.f);
        acc.z = fmaxf(acc.z, 0.f); acc.w = fmaxf(acc.w, 0.f);
    }
    if (FUSE_POOL) {
        float4 w4 = ((const float4*)Wn)[q];
        float s = acc.x * w4.x + acc.y * w4.y + acc.z * w4.z + acc.w * w4.w;
        s += __shfl_xor(s, 1);
        s += __shfl_xor(s, 2);
        if (q == 0) {
            int g = batch[n];
            atomicAdd(&pool[g], s);
            atomicAdd(&gcnt[g], 1);
        }
    } else {
        float4 vals[4];
        vals[0] = acc;
        vals[1] = shfl_xor4(acc, 1);
        vals[2] = shfl_xor4(acc, 2);
        vals[3] = shfl_xor4(acc, 3);
        const float4* sW4 = (const float4*)sW;
        float4 hv = make_float4(0.f, 0.f, 0.f, 0.f);
#pragma unroll
        for (int m = 0; m < 4; m++) {
            float4 v = vals[m];
            int rb = (q ^ m) << 2;
            float4 w;
            w = sW4[(rb + 0) * 4 + q];
            hv.x += v.x * w.x; hv.y += v.x * w.y; hv.z += v.x * w.z; hv.w += v.x * w.w;
            w = sW4[(rb + 1) * 4 + q];
            hv.x += v.y * w.x; hv.y += v.y * w.y; hv.z += v.y * w.z; hv.w += v.y * w.w;
            w = sW4[(rb + 2) * 4 + q];
            hv.x += v.z * w.x; hv.y += v.z * w.y; hv.z += v.z * w.z; hv.w += v.z * w.w;
            w = sW4[(rb + 3) * 4 + q];
            hv.x += v.w * w.x; hv.y += v.w * w.y; hv.z += v.w * w.z; hv.w += v.w * w.w;
        }
        hs_out[(size_t)n * 4 + q] = pack4(hv.x * dn, hv.y * dn, hv.z * dn, hv.w * dn);
    }
}

__global__ void finalize(const float* __restrict__ pool, const int* __restrict__ gcnt,
                         const float* __restrict__ bo, float* __restrict__ out) {
    int g = blockIdx.x * 256 + threadIdx.x;
    if (g < NG) {
        float c = fmaxf((float)gcnt[g], 1.0f);
        out[g] = pool[g] / c + bo[0];
    }
}

extern "C" void kernel_launch(void* const* d_in, const int* in_sizes, int n_in,
                              void* d_out, int out_size, void* d_ws, size_t ws_size,
                              hipStream_t stream) {
    const int*   types = (const int*)d_in[0];
    const int*   pos   = (const int*)d_in[1];
    const int*   ei    = (const int*)d_in[2];   // [2, E]: src then dst
    const int*   batch = (const int*)d_in[3];
    const float* W1  = (const float*)d_in[4];
    const float* b1  = (const float*)d_in[5];
    const float* W2  = (const float*)d_in[6];
    const float* b2  = (const float*)d_in[7];
    const float* Wg0 = (const float*)d_in[8];
    const float* bg0 = (const float*)d_in[9];
    const float* Wg1 = (const float*)d_in[10];
    const float* bg1 = (const float*)d_in[11];
    const float* Wg2 = (const float*)d_in[12];
    const float* bg2 = (const float*)d_in[13];
    const float* Wo  = (const float*)d_in[14];
    const float* bo  = (const float*)d_in[15];
    float* out = (float*)d_out;

    const int* esrc = ei;
    const int* edst = ei + NE;

    // ---- workspace layout (ints) ----
    int*   bcnt  = (int*)d_ws;                   // 512  (zeroed)
    int*   bfill = bcnt + 512;                   // 512  (zeroed)
    float* pool  = (float*)(bfill + 512);        // 1024 (zeroed)
    int*   gcnt  = (int*)(pool + NG);            // 1024 (zeroed)
    int*   bbase = gcnt + NG;                    // 512
    int*   cnt   = bbase + 512;                  // NP
    int*   offs  = cnt + NP;                     // NP
    float* dis   = (float*)(offs + NP);          // NP
    unsigned int* pk = (unsigned int*)(dis + NP);// NP  ({class,fp16 dis} table)
    int*   srcs  = (int*)(pk + NP);              // NE  (16B-aligned)
    int*   part  = srcs + NE;                    // NE  (hs buffers alias this)
    uint2* hsA   = (uint2*)part;                 // NP*4 uint2 = 3.2 MB
    uint2* hsB   = (uint2*)(part + NE / 2);      // 3.2 MB (part is 12.8 MB)
    (void)ws_size; (void)n_in; (void)in_sizes; (void)out_size;

    hipMemsetAsync(d_ws, 0, (size_t)(1024 + 2 * NG) * sizeof(int), stream);

    const int QB  = (NN * 4 + 255) / 256;        // 1563
    const int QB2 = (NN * 2 + 255) / 256;        // 782

    hist_buckets<<<NBLK, 256, 0, stream>>>(edst, bcnt);
    scan_buckets<<<1, 512, 0, stream>>>(bcnt, bbase);
    partition<<<NBLK, 256, 0, stream>>>(esrc, edst, bbase, bfill, part);
    build_csr<<<NBUCK, 256, 0, stream>>>(part, bbase, bcnt, types, pos,
                                         cnt, offs, dis, pk, srcs);

    // layer 0 (fused rank-9): 4B/edge pk gather -> hs1 = (relu(...)@Wg1)*dis
    agg0_tf<<<QB2, 256, 0, stream>>>(pk, srcs, offs, cnt, dis, W1, b1, W2, b2,
                                     Wg0, bg0, Wg1, hsA);
    // layer 1 agg + relu + transform Wg2 -> hs2
    agg_tf<1, 0><<<QB, 256, 0, stream>>>(hsA, srcs, offs, cnt, dis, bg1, Wg2, hsB,
                                         batch, pool, gcnt);
    // layer 2 agg (no relu) + Wo dot + pool
    agg_tf<0, 1><<<QB, 256, 0, stream>>>(hsB, srcs, offs, cnt, dis, bg2, Wo, hsA /*unused*/,
                                         batch, pool, gcnt);

    finalize<<<(NG + 255) / 256, 256, 0, stream>>>(pool, gcnt, bo, out);
}